// Round 9
// baseline (238.672 us; speedup 1.0000x reference)
//
#include <hip/hip_runtime.h>
#include <hip/hip_bf16.h>
#include <math.h>

// B=4, T=2048, C=1024, H=16, D=64, M = B*T = 8192

typedef short bf16x8 __attribute__((ext_vector_type(8)));
typedef float f32x4 __attribute__((ext_vector_type(4)));
typedef _Float16 f16x4 __attribute__((ext_vector_type(4)));

__device__ __forceinline__ short f2b(float f) {
    unsigned u = __float_as_uint(f);
    u = (u + 0x7fffu + ((u >> 16) & 1u)) >> 16;
    return (short)u;
}
__device__ __forceinline__ float b2f(short s) {
    return __uint_as_float(((unsigned)(unsigned short)s) << 16);
}

// ---------------------------------------------------------------- prep: cast x (blocks 0..8191)
//                                       + cast/transpose 4 weight mats (blocks 8192..9215)
__global__ __launch_bounds__(256) void prep_kernel(const float* __restrict__ x, short* __restrict__ xb,
                                                   const float* W0, const float* W1,
                                                   const float* W2, const float* W3,
                                                   short* O0, short* O1, short* O2, short* O3) {
    int tid = threadIdx.x;
    if (blockIdx.x < 8192) {
        int idx = blockIdx.x * 256 + tid;
        float4 v = ((const float4*)x)[idx];
        short4 o;
        o.x = f2b(v.x); o.y = f2b(v.y); o.z = f2b(v.z); o.w = f2b(v.w);
        ((short4*)xb)[idx] = o;
        return;
    }
    int wid = blockIdx.x - 8192;         // 0..1023
    const float* W; short* O;
    switch (wid >> 8) {
        case 0: W = W0; O = O0; break;
        case 1: W = W1; O = O1; break;
        case 2: W = W2; O = O2; break;
        default: W = W3; O = O3; break;
    }
    int rem = wid & 255;
    int n0 = (rem >> 4) * 64, k0 = (rem & 15) * 64;
    __shared__ __align__(16) float Ls[64 * 68];
    #pragma unroll
    for (int it = 0; it < 4; ++it) {
        int c = tid + it * 256;
        int r = c >> 4, off = (c & 15) * 4;
        *(float4*)&Ls[r * 68 + off] = *(const float4*)&W[(k0 + r) * 1024 + n0 + off];
    }
    __syncthreads();
    #pragma unroll
    for (int it = 0; it < 2; ++it) {
        int c = tid + it * 256;
        int n = c >> 3, koff = (c & 7) * 8;
        union { short s[8]; int4 v; } u;
        #pragma unroll
        for (int k = 0; k < 8; ++k) u.s[k] = f2b(Ls[(koff + k) * 68 + n]);
        *(int4*)&O[(n0 + n) * 1024 + k0 + koff] = u.v;
    }
}

// ---------------------------------------------------------------- GEMM 128x256, BK=64 (R2 schedule)
// kk-split balanced phases (8 ds_read + 16 indep MFMA each) with one-phase read-ahead
// (counted lgkmcnt(8)); triple-buffered staging with counted vmcnt(3); 2 barriers/tile.
// T2 st_16x32 swizzle via pre-swizzled global src col (bank conflicts = 0).
// MODE==0 && z==2 (V): epilogue writes f16 DIRECTLY TRANSPOSED to [bh][d][t] (no vtrans kernel).
template<int MODE>
__global__ __launch_bounds__(512, 2) void gemm8_kernel(const short* __restrict__ A,
                                                       const short* Bt0, const short* Bt1, const short* Bt2,
                                                       const float* b0, const float* b1, const float* b2,
                                                       float s0, float s1, float s2,
                                                       void* O0, void* O1, void* O2) {
    int z = blockIdx.z;
    const short* Bt   = (z == 0) ? Bt0 : (z == 1) ? Bt1 : Bt2;
    const float* bias = (z == 0) ? b0  : (z == 1) ? b1  : b2;
    float scl         = (z == 0) ? s0  : (z == 1) ? s1  : s2;
    void* Out         = (z == 0) ? O0  : (z == 1) ? O1  : O2;

    __shared__ __align__(16) short lds[73728];

    int tid = threadIdx.x;
    int w = tid >> 6, lane = tid & 63, quad = lane >> 4, l15 = lane & 15;
    int m0 = blockIdx.x * 128, n0 = blockIdx.y * 256;

    int srccol = ((lane & 3) * 8) ^ ((lane & 32) ? 16 : 0);
    const short* pA0 = A  + (m0 + w * 16 + (lane >> 2)) * 1024 + srccol;
    const short* pA1 = pA0 + 32;
    const short* pB0 = Bt + (n0 + (2 * w) * 16 + (lane >> 2)) * 1024 + srccol;
    const short* pB1 = pB0 + 32;
    const short* pB2 = pB0 + 16 * 1024;
    const short* pB3 = pB2 + 32;

    int dA = (w * 2) * 512;
    int dB = 24576 + (w * 4) * 512;

    int offR = l15 * 64 + ((quad * 16) ^ ((l15 & 8) << 2));
    int ma4 = (w >> 2) * 4;
    int nb2 = (w & 3) * 2;
    int jrow0 = nb2, jrow1 = nb2 + 1, jrow2 = nb2 + 8, jrow3 = nb2 + 9;
    const char* ldsb = (const char*)lds;

    f32x4 acc[4][4] = {};
    bf16x8 afA[4], bfA[4], afB[4], bfB[4];

#define STG(p, off) __builtin_amdgcn_global_load_lds( \
        (const __attribute__((address_space(1))) unsigned int*)(p), \
        (__attribute__((address_space(3))) unsigned int*)&lds[off], 16, 0, 0)
#define RD(base, row, kk) (*(const bf16x8*)(ldsb + (base) + ((row) * 2 + (kk)) * 1024 + offR))

    STG(pA0,      dA);                 STG(pA1,      dA + 512);
    STG(pB0,      dB);                 STG(pB1,      dB + 512);
    STG(pB2,      dB + 1024);          STG(pB3,      dB + 1536);
    STG(pA0 + 64, 8192 + dA);          STG(pA1 + 64, 8192 + dA + 512);
    STG(pB0 + 64, 16384 + dB);         STG(pB1 + 64, 16384 + dB + 512);
    STG(pB2 + 64, 16384 + dB + 1024);  STG(pB3 + 64, 16384 + dB + 1536);
    asm volatile("s_waitcnt vmcnt(6)" ::: "memory");
    __builtin_amdgcn_s_barrier();
    __builtin_amdgcn_sched_barrier(0);

    #pragma unroll
    for (int i = 0; i < 4; ++i) afA[i] = RD(0, ma4 + i, 0);
    bfA[0] = RD(49152, jrow0, 0); bfA[1] = RD(49152, jrow1, 0);
    bfA[2] = RD(49152, jrow2, 0); bfA[3] = RD(49152, jrow3, 0);

    #pragma unroll
    for (int t = 0; t < 16; ++t) {
        const int rs  = t % 3;
        const int rs1 = (t + 1) % 3;
        const int ss  = (t + 2) % 3;
        const int Ar  = rs * 16384;
        const int Br  = 49152 + rs * 32768;
        const int Ar1 = rs1 * 16384;
        const int Br1 = 49152 + rs1 * 32768;

        #pragma unroll
        for (int i = 0; i < 4; ++i) afB[i] = RD(Ar, ma4 + i, 1);
        bfB[0] = RD(Br, jrow0, 1); bfB[1] = RD(Br, jrow1, 1);
        bfB[2] = RD(Br, jrow2, 1); bfB[3] = RD(Br, jrow3, 1);
        if (t + 2 < 16) {
            STG(pA0 + (t + 2) * 64, ss * 8192 + dA);
            STG(pA1 + (t + 2) * 64, ss * 8192 + dA + 512);
            STG(pB0 + (t + 2) * 64, ss * 16384 + dB);
        }
        asm volatile("s_waitcnt lgkmcnt(8)" ::: "memory");
        __builtin_amdgcn_sched_barrier(0);
        __builtin_amdgcn_s_setprio(1);
        #pragma unroll
        for (int i = 0; i < 4; ++i)
            #pragma unroll
            for (int j = 0; j < 4; ++j)
                acc[i][j] = __builtin_amdgcn_mfma_f32_16x16x32_bf16(afA[i], bfA[j], acc[i][j], 0, 0, 0);
        __builtin_amdgcn_s_setprio(0);
        if (t < 14) {
            asm volatile("s_waitcnt vmcnt(3)" ::: "memory");
        } else if (t == 14) {
            asm volatile("s_waitcnt vmcnt(0)" ::: "memory");
        }
        __builtin_amdgcn_s_barrier();
        __builtin_amdgcn_sched_barrier(0);

        if (t < 15) {
            #pragma unroll
            for (int i = 0; i < 4; ++i) afA[i] = RD(Ar1, ma4 + i, 0);
            bfA[0] = RD(Br1, jrow0, 0); bfA[1] = RD(Br1, jrow1, 0);
            bfA[2] = RD(Br1, jrow2, 0); bfA[3] = RD(Br1, jrow3, 0);
        }
        if (t + 2 < 16) {
            STG(pB1 + (t + 2) * 64, ss * 16384 + dB + 512);
            STG(pB2 + (t + 2) * 64, ss * 16384 + dB + 1024);
            STG(pB3 + (t + 2) * 64, ss * 16384 + dB + 1536);
        }
        if (t < 15) {
            asm volatile("s_waitcnt lgkmcnt(8)" ::: "memory");
        } else {
            asm volatile("s_waitcnt lgkmcnt(0)" ::: "memory");
        }
        __builtin_amdgcn_sched_barrier(0);
        __builtin_amdgcn_s_setprio(1);
        #pragma unroll
        for (int i = 0; i < 4; ++i)
            #pragma unroll
            for (int j = 0; j < 4; ++j)
                acc[i][j] = __builtin_amdgcn_mfma_f32_16x16x32_bf16(afB[i], bfB[j], acc[i][j], 0, 0, 0);
        __builtin_amdgcn_s_setprio(0);
        if (t < 15) {
            __builtin_amdgcn_s_barrier();
            __builtin_amdgcn_sched_barrier(0);
        }
    }
#undef STG
#undef RD

    int mrow = m0 + (w >> 2) * 64;
    int ncol = n0 + (w & 3) * 32;
    #pragma unroll
    for (int i = 0; i < 4; ++i) {
        #pragma unroll
        for (int j = 0; j < 4; ++j) {
            int gn = ncol + (j >> 1) * 128 + (j & 1) * 16 + l15;
            float bv = bias[gn];
            if (MODE == 0 && z == 2) {
                // V: write f16 directly transposed [bh][d][t]; r-values are consecutive t
                int gm0 = mrow + i * 16 + quad * 4;
                int b = gm0 >> 11, tt = gm0 & 2047, h = gn >> 6, d = gn & 63;
                f16x4 hv;
                #pragma unroll
                for (int r = 0; r < 4; ++r) hv[r] = (_Float16)((acc[i][j][r] + bv) * scl);
                *(f16x4*)&((_Float16*)Out)[((b * 16 + h) * 64 + d) * 2048 + tt] = hv;
            } else {
                #pragma unroll
                for (int r = 0; r < 4; ++r) {
                    int gm = mrow + i * 16 + quad * 4 + r;
                    float v = (acc[i][j][r] + bv) * scl;
                    if (MODE == 0) {
                        int b = gm >> 11, tt = gm & 2047, h = gn >> 6, d = gn & 63;
                        ((short*)Out)[(((b * 16 + h) * 2048) + tt) * 64 + d] = f2b(v);
                    } else {
                        ((float*)Out)[gm * 1024 + gn] = v;
                    }
                }
            }
        }
    }
}

// ---------------------------------------------------------------- flash attention (R9)
// R6 geometry (1024 blocks, 128-row Q, longest-first) + K double-buffer / V single-buffer:
//  - K(si+1) staged at iter top (hidden under iter si's j-loop).
//  - V(si+1) staged at iter END, after lgkmcnt(0)+barrier (V(si) reads drained); its
//    landing deadline is iter si+1's PV, so QK^T+softmax (~1500cy) hides HBM latency.
//  - Plain vmcnt(0) at iter top: outstanding VMEM there is exactly {K(si), V(si)} -> no
//    over-wait, no counting needed. Raw s_barrier (not __syncthreads). 2 barriers/iter.
// LDS 48 KB -> 3 blocks/CU (vs R8's 64 KB / 2 blocks: dbuf gain without the occupancy loss).
__global__ __launch_bounds__(256, 3) void attn_kernel(const short* __restrict__ Q,
                                                      const short* __restrict__ K,
                                                      const _Float16* __restrict__ Vt,
                                                      short* __restrict__ Y) {
    __shared__ __align__(16) short    Ks[2][128 * 64];   // 2 x 16384 B, swizzled
    __shared__ __align__(16) _Float16 Vs[64 * 128];      // 16384 B, swizzled

    int tid = threadIdx.x;
    int w = tid >> 6, lane = tid & 63, quad = lane >> 4, l15 = lane & 15;
    int idx = blockIdx.x;
    int qi = 15 - (idx >> 6);   // longest blocks first
    int bh = idx & 63;

    const short* Qh = Q + bh * 2048 * 64;
    const short* Kh = K + bh * 2048 * 64;
    const _Float16* Vh = Vt + bh * 64 * 2048;

    // Q fragments (B-operand: lane l15 = q, k = quad*8+j)
    bf16x8 qf[2][2];
    #pragma unroll
    for (int i = 0; i < 2; ++i)
        #pragma unroll
        for (int kh = 0; kh < 2; ++kh) {
            int t = qi * 128 + w * 32 + i * 16 + l15;
            qf[i][kh] = *(const bf16x8*)&Qh[t * 64 + kh * 32 + quad * 8];
        }

    int krow = lane >> 3;
    int kchunk = ((lane & 7) ^ krow) * 8;
    int vrow = lane >> 4;
    int vchunk = ((lane & 15) ^ (w * 4 + vrow)) * 8;

    int t7 = l15 & 7;
    int kf0_off = ((quad ^ t7) * 8);
    int kf1_off = (((quad + 4) ^ t7) * 8);
    int vsub = (quad & 1) * 4;
    int vchi = quad >> 1;

    f32x4 o[2][4] = {};
    float lsum[2] = {0.f, 0.f};

#define STGK(si_, buf_) do { \
    const short* Kt_ = Kh + (si_) * 128 * 64; \
    _Pragma("unroll") \
    for (int it = 0; it < 4; ++it) { \
        int kr0 = it * 32 + w * 8; \
        __builtin_amdgcn_global_load_lds( \
            (const __attribute__((address_space(1))) unsigned int*)&Kt_[(kr0 + krow) * 64 + kchunk], \
            (__attribute__((address_space(3))) unsigned int*)&Ks[buf_][kr0 * 64], 16, 0, 0); \
    } } while (0)
#define STGV(si_) do { \
    const _Float16* Vp_ = Vh + (si_) * 128; \
    _Pragma("unroll") \
    for (int it = 0; it < 4; ++it) { \
        int vr0 = it * 16 + w * 4; \
        __builtin_amdgcn_global_load_lds( \
            (const __attribute__((address_space(1))) unsigned int*)&Vp_[(vr0 + vrow) * 2048 + vchunk], \
            (__attribute__((address_space(3))) unsigned int*)&Vs[vr0 * 128], 16, 0, 0); \
    } } while (0)

    STGK(0, 0);
    STGV(0);

    for (int si = 0; si <= qi; ++si) {
        // top: only K(si)+V(si) are outstanding -> plain drain, then publish
        asm volatile("s_waitcnt vmcnt(0)" ::: "memory");
        __builtin_amdgcn_s_barrier();
        __builtin_amdgcn_sched_barrier(0);

        if (si < qi) STGK(si + 1, (si + 1) & 1);   // hidden under this iter's j-loop

        const short* Ksb = Ks[si & 1];
        bool diag = (si == qi);

        #pragma unroll
        for (int j = 0; j < 8; ++j) {
            int trow = (j * 16 + l15) * 64;
            bf16x8 kf0 = *(const bf16x8*)&Ksb[trow + kf0_off];
            bf16x8 kf1 = *(const bf16x8*)&Ksb[trow + kf1_off];
            f16x4 pfv[2];
            #pragma unroll
            for (int i = 0; i < 2; ++i) {
                f32x4 a = {};
                a = __builtin_amdgcn_mfma_f32_16x16x32_bf16(kf0, qf[i][0], a, 0, 0, 0);
                a = __builtin_amdgcn_mfma_f32_16x16x32_bf16(kf1, qf[i][1], a, 0, 0, 0);
                if (diag) {
                    int qrel = w * 32 + i * 16 + l15;
                    #pragma unroll
                    for (int r = 0; r < 4; ++r)
                        if (j * 16 + quad * 4 + r > qrel) a[r] = -1e30f;
                }
                float p0 = __builtin_amdgcn_exp2f(a[0]);
                float p1 = __builtin_amdgcn_exp2f(a[1]);
                float p2 = __builtin_amdgcn_exp2f(a[2]);
                float p3 = __builtin_amdgcn_exp2f(a[3]);
                lsum[i] += (p0 + p1) + (p2 + p3);
                pfv[i][0] = (_Float16)p0;
                pfv[i][1] = (_Float16)p1;
                pfv[i][2] = (_Float16)p2;
                pfv[i][3] = (_Float16)p3;
            }
            int vc = (j * 2 + vchi);
            #pragma unroll
            for (int mt = 0; mt < 4; ++mt) {
                int d = mt * 16 + l15;
                f16x4 vf = *(const f16x4*)&Vs[d * 128 + ((vc ^ l15) * 8) + vsub];
                o[0][mt] = __builtin_amdgcn_mfma_f32_16x16x16f16(vf, pfv[0], o[0][mt], 0, 0, 0);
                o[1][mt] = __builtin_amdgcn_mfma_f32_16x16x16f16(vf, pfv[1], o[1][mt], 0, 0, 0);
            }
        }

        if (si < qi) {
            asm volatile("s_waitcnt lgkmcnt(0)" ::: "memory");  // all Vs (and Ks) reads complete
            __builtin_amdgcn_s_barrier();                        // every wave past its reads
            __builtin_amdgcn_sched_barrier(0);
            STGV(si + 1);                                        // deadline: next iter's PV
        }
    }
#undef STGK
#undef STGV

    int b = bh >> 4, h = bh & 15;
    #pragma unroll
    for (int i = 0; i < 2; ++i) {
        float l = lsum[i];
        l += __shfl_xor(l, 16);
        l += __shfl_xor(l, 32);
        float rinv = 1.0f / l;
        int q = qi * 128 + w * 32 + i * 16 + l15;
        short* yrow = &Y[(b * 2048 + q) * 1024 + h * 64];
        #pragma unroll
        for (int mt = 0; mt < 4; ++mt) {
            short4 s4;
            s4.x = f2b(o[i][mt][0] * rinv);
            s4.y = f2b(o[i][mt][1] * rinv);
            s4.z = f2b(o[i][mt][2] * rinv);
            s4.w = f2b(o[i][mt][3] * rinv);
            *(short4*)&yrow[mt * 16 + quad * 4] = s4;
        }
    }
}

// ----------------------------------------------------------------
extern "C" void kernel_launch(void* const* d_in, const int* in_sizes, int n_in,
                              void* d_out, int out_size, void* d_ws, size_t ws_size,
                              hipStream_t stream) {
    const float* x  = (const float*)d_in[0];
    const float* Wk = (const float*)d_in[1];
    const float* bk = (const float*)d_in[2];
    const float* Wq = (const float*)d_in[3];
    const float* bq = (const float*)d_in[4];
    const float* Wv = (const float*)d_in[5];
    const float* bv = (const float*)d_in[6];
    const float* Wp = (const float*)d_in[7];
    const float* bp = (const float*)d_in[8];

    char* ws = (char*)d_ws;
    short*     xb  = (short*)(ws + 0);          // 16 MB  x bf16 [8192][1024]
    short*     Wqt = (short*)(ws + 16777216);   // 2 MB each, bf16 [N][K]
    short*     Wkt = (short*)(ws + 18874368);
    short*     Wvt = (short*)(ws + 20971520);
    short*     Wpt = (short*)(ws + 23068672);
    short*     Qb  = (short*)(ws + 25165824);   // 16 MB [B,H,T,D] (pre-scaled by log2e/8)
    short*     Kb  = (short*)(ws + 41943040);   // 16 MB [B,H,T,D]
    _Float16*  Vtb = (_Float16*)(ws + 75497472);// 16 MB [B,H,D,T] f16 (written directly by gemm z=2)
    short*     Yb  = (short*)(ws + 92274688);   // 16 MB [B*T][C]

    prep_kernel<<<9216, 256, 0, stream>>>(x, xb, Wq, Wk, Wv, Wp, Wqt, Wkt, Wvt, Wpt);
    gemm8_kernel<0><<<dim3(64, 4, 3), 512, 0, stream>>>(xb, Wqt, Wkt, Wvt, bq, bk, bv,
                                                        0.18033688011112042f /* log2e/8 */, 1.0f, 1.0f,
                                                        (void*)Qb, (void*)Kb, (void*)Vtb);
    attn_kernel<<<1024, 256, 0, stream>>>(Qb, Kb, Vtb, Yb);
    gemm8_kernel<1><<<dim3(64, 4, 1), 512, 0, stream>>>(Yb, Wpt, nullptr, nullptr,
                                                        bp, nullptr, nullptr,
                                                        1.0f, 1.0f, 1.0f,
                                                        (void*)d_out, nullptr, nullptr);
}

// Round 11
// 235.254 us; speedup vs baseline: 1.0145x; 1.0145x over previous
//
#include <hip/hip_runtime.h>
#include <hip/hip_bf16.h>
#include <math.h>

// B=4, T=2048, C=1024, H=16, D=64, M = B*T = 8192

typedef short bf16x8 __attribute__((ext_vector_type(8)));
typedef float f32x4 __attribute__((ext_vector_type(4)));
typedef _Float16 f16x4 __attribute__((ext_vector_type(4)));
typedef __fp16 fp16x2 __attribute__((ext_vector_type(2)));

__device__ __forceinline__ short f2b(float f) {
    unsigned u = __float_as_uint(f);
    u = (u + 0x7fffu + ((u >> 16) & 1u)) >> 16;
    return (short)u;
}
__device__ __forceinline__ float b2f(short s) {
    return __uint_as_float(((unsigned)(unsigned short)s) << 16);
}

// ---------------------------------------------------------------- prep: cast x (blocks 0..8191)
//                                       + cast/transpose 4 weight mats (blocks 8192..9215)
__global__ __launch_bounds__(256) void prep_kernel(const float* __restrict__ x, short* __restrict__ xb,
                                                   const float* W0, const float* W1,
                                                   const float* W2, const float* W3,
                                                   short* O0, short* O1, short* O2, short* O3) {
    int tid = threadIdx.x;
    if (blockIdx.x < 8192) {
        int idx = blockIdx.x * 256 + tid;
        float4 v = ((const float4*)x)[idx];
        short4 o;
        o.x = f2b(v.x); o.y = f2b(v.y); o.z = f2b(v.z); o.w = f2b(v.w);
        ((short4*)xb)[idx] = o;
        return;
    }
    int wid = blockIdx.x - 8192;         // 0..1023
    const float* W; short* O;
    switch (wid >> 8) {
        case 0: W = W0; O = O0; break;
        case 1: W = W1; O = O1; break;
        case 2: W = W2; O = O2; break;
        default: W = W3; O = O3; break;
    }
    int rem = wid & 255;
    int n0 = (rem >> 4) * 64, k0 = (rem & 15) * 64;
    __shared__ __align__(16) float Ls[64 * 68];
    #pragma unroll
    for (int it = 0; it < 4; ++it) {
        int c = tid + it * 256;
        int r = c >> 4, off = (c & 15) * 4;
        *(float4*)&Ls[r * 68 + off] = *(const float4*)&W[(k0 + r) * 1024 + n0 + off];
    }
    __syncthreads();
    #pragma unroll
    for (int it = 0; it < 2; ++it) {
        int c = tid + it * 256;
        int n = c >> 3, koff = (c & 7) * 8;
        union { short s[8]; int4 v; } u;
        #pragma unroll
        for (int k = 0; k < 8; ++k) u.s[k] = f2b(Ls[(koff + k) * 68 + n]);
        *(int4*)&O[(n0 + n) * 1024 + k0 + koff] = u.v;
    }
}

// ---------------------------------------------------------------- GEMM 128x256, BK=64 (R2 schedule)
// kk-split balanced phases (8 ds_read + 16 indep MFMA each) with one-phase read-ahead
// (counted lgkmcnt(8)); triple-buffered staging with counted vmcnt(3); 2 barriers/tile.
// T2 st_16x32 swizzle via pre-swizzled global src col (bank conflicts = 0).
// MODE==0 && z==2 (V): epilogue writes f16 DIRECTLY TRANSPOSED to [bh][d][t] (no vtrans kernel).
template<int MODE>
__global__ __launch_bounds__(512, 2) void gemm8_kernel(const short* __restrict__ A,
                                                       const short* Bt0, const short* Bt1, const short* Bt2,
                                                       const float* b0, const float* b1, const float* b2,
                                                       float s0, float s1, float s2,
                                                       void* O0, void* O1, void* O2) {
    int z = blockIdx.z;
    const short* Bt   = (z == 0) ? Bt0 : (z == 1) ? Bt1 : Bt2;
    const float* bias = (z == 0) ? b0  : (z == 1) ? b1  : b2;
    float scl         = (z == 0) ? s0  : (z == 1) ? s1  : s2;
    void* Out         = (z == 0) ? O0  : (z == 1) ? O1  : O2;

    __shared__ __align__(16) short lds[73728];

    int tid = threadIdx.x;
    int w = tid >> 6, lane = tid & 63, quad = lane >> 4, l15 = lane & 15;
    int m0 = blockIdx.x * 128, n0 = blockIdx.y * 256;

    int srccol = ((lane & 3) * 8) ^ ((lane & 32) ? 16 : 0);
    const short* pA0 = A  + (m0 + w * 16 + (lane >> 2)) * 1024 + srccol;
    const short* pA1 = pA0 + 32;
    const short* pB0 = Bt + (n0 + (2 * w) * 16 + (lane >> 2)) * 1024 + srccol;
    const short* pB1 = pB0 + 32;
    const short* pB2 = pB0 + 16 * 1024;
    const short* pB3 = pB2 + 32;

    int dA = (w * 2) * 512;
    int dB = 24576 + (w * 4) * 512;

    int offR = l15 * 64 + ((quad * 16) ^ ((l15 & 8) << 2));
    int ma4 = (w >> 2) * 4;
    int nb2 = (w & 3) * 2;
    int jrow0 = nb2, jrow1 = nb2 + 1, jrow2 = nb2 + 8, jrow3 = nb2 + 9;
    const char* ldsb = (const char*)lds;

    f32x4 acc[4][4] = {};
    bf16x8 afA[4], bfA[4], afB[4], bfB[4];

#define STG(p, off) __builtin_amdgcn_global_load_lds( \
        (const __attribute__((address_space(1))) unsigned int*)(p), \
        (__attribute__((address_space(3))) unsigned int*)&lds[off], 16, 0, 0)
#define RD(base, row, kk) (*(const bf16x8*)(ldsb + (base) + ((row) * 2 + (kk)) * 1024 + offR))

    STG(pA0,      dA);                 STG(pA1,      dA + 512);
    STG(pB0,      dB);                 STG(pB1,      dB + 512);
    STG(pB2,      dB + 1024);          STG(pB3,      dB + 1536);
    STG(pA0 + 64, 8192 + dA);          STG(pA1 + 64, 8192 + dA + 512);
    STG(pB0 + 64, 16384 + dB);         STG(pB1 + 64, 16384 + dB + 512);
    STG(pB2 + 64, 16384 + dB + 1024);  STG(pB3 + 64, 16384 + dB + 1536);
    asm volatile("s_waitcnt vmcnt(6)" ::: "memory");
    __builtin_amdgcn_s_barrier();
    __builtin_amdgcn_sched_barrier(0);

    #pragma unroll
    for (int i = 0; i < 4; ++i) afA[i] = RD(0, ma4 + i, 0);
    bfA[0] = RD(49152, jrow0, 0); bfA[1] = RD(49152, jrow1, 0);
    bfA[2] = RD(49152, jrow2, 0); bfA[3] = RD(49152, jrow3, 0);

    #pragma unroll
    for (int t = 0; t < 16; ++t) {
        const int rs  = t % 3;
        const int rs1 = (t + 1) % 3;
        const int ss  = (t + 2) % 3;
        const int Ar  = rs * 16384;
        const int Br  = 49152 + rs * 32768;
        const int Ar1 = rs1 * 16384;
        const int Br1 = 49152 + rs1 * 32768;

        #pragma unroll
        for (int i = 0; i < 4; ++i) afB[i] = RD(Ar, ma4 + i, 1);
        bfB[0] = RD(Br, jrow0, 1); bfB[1] = RD(Br, jrow1, 1);
        bfB[2] = RD(Br, jrow2, 1); bfB[3] = RD(Br, jrow3, 1);
        if (t + 2 < 16) {
            STG(pA0 + (t + 2) * 64, ss * 8192 + dA);
            STG(pA1 + (t + 2) * 64, ss * 8192 + dA + 512);
            STG(pB0 + (t + 2) * 64, ss * 16384 + dB);
        }
        asm volatile("s_waitcnt lgkmcnt(8)" ::: "memory");
        __builtin_amdgcn_sched_barrier(0);
        __builtin_amdgcn_s_setprio(1);
        #pragma unroll
        for (int i = 0; i < 4; ++i)
            #pragma unroll
            for (int j = 0; j < 4; ++j)
                acc[i][j] = __builtin_amdgcn_mfma_f32_16x16x32_bf16(afA[i], bfA[j], acc[i][j], 0, 0, 0);
        __builtin_amdgcn_s_setprio(0);
        if (t < 14) {
            asm volatile("s_waitcnt vmcnt(3)" ::: "memory");
        } else if (t == 14) {
            asm volatile("s_waitcnt vmcnt(0)" ::: "memory");
        }
        __builtin_amdgcn_s_barrier();
        __builtin_amdgcn_sched_barrier(0);

        if (t < 15) {
            #pragma unroll
            for (int i = 0; i < 4; ++i) afA[i] = RD(Ar1, ma4 + i, 0);
            bfA[0] = RD(Br1, jrow0, 0); bfA[1] = RD(Br1, jrow1, 0);
            bfA[2] = RD(Br1, jrow2, 0); bfA[3] = RD(Br1, jrow3, 0);
        }
        if (t + 2 < 16) {
            STG(pB1 + (t + 2) * 64, ss * 16384 + dB + 512);
            STG(pB2 + (t + 2) * 64, ss * 16384 + dB + 1024);
            STG(pB3 + (t + 2) * 64, ss * 16384 + dB + 1536);
        }
        if (t < 15) {
            asm volatile("s_waitcnt lgkmcnt(8)" ::: "memory");
        } else {
            asm volatile("s_waitcnt lgkmcnt(0)" ::: "memory");
        }
        __builtin_amdgcn_sched_barrier(0);
        __builtin_amdgcn_s_setprio(1);
        #pragma unroll
        for (int i = 0; i < 4; ++i)
            #pragma unroll
            for (int j = 0; j < 4; ++j)
                acc[i][j] = __builtin_amdgcn_mfma_f32_16x16x32_bf16(afB[i], bfB[j], acc[i][j], 0, 0, 0);
        __builtin_amdgcn_s_setprio(0);
        if (t < 15) {
            __builtin_amdgcn_s_barrier();
            __builtin_amdgcn_sched_barrier(0);
        }
    }
#undef STG
#undef RD

    int mrow = m0 + (w >> 2) * 64;
    int ncol = n0 + (w & 3) * 32;
    #pragma unroll
    for (int i = 0; i < 4; ++i) {
        #pragma unroll
        for (int j = 0; j < 4; ++j) {
            int gn = ncol + (j >> 1) * 128 + (j & 1) * 16 + l15;
            float bv = bias[gn];
            if (MODE == 0 && z == 2) {
                // V: write f16 directly transposed [bh][d][t]; r-values are consecutive t
                int gm0 = mrow + i * 16 + quad * 4;
                int b = gm0 >> 11, tt = gm0 & 2047, h = gn >> 6, d = gn & 63;
                f16x4 hv;
                #pragma unroll
                for (int r = 0; r < 4; ++r) hv[r] = (_Float16)((acc[i][j][r] + bv) * scl);
                *(f16x4*)&((_Float16*)Out)[((b * 16 + h) * 64 + d) * 2048 + tt] = hv;
            } else {
                #pragma unroll
                for (int r = 0; r < 4; ++r) {
                    int gm = mrow + i * 16 + quad * 4 + r;
                    float v = (acc[i][j][r] + bv) * scl;
                    if (MODE == 0) {
                        int b = gm >> 11, tt = gm & 2047, h = gn >> 6, d = gn & 63;
                        ((short*)Out)[(((b * 16 + h) * 2048) + tt) * 64 + d] = f2b(v);
                    } else {
                        ((float*)Out)[gm * 1024 + gn] = v;
                    }
                }
            }
        }
    }
}

// ---------------------------------------------------------------- flash attention (R11 = R10 + cvt type fix)
// R9 staging (K dbuf at iter top / V single-buffer staged at iter end, plain vmcnt(0) at
// top, raw s_barrier) + software-pipelined j-loop:
//  - QK(j) MFMAs issue at loop top using kf pre-read in iteration j-1 (prefetch kf(j+1)
//    right after) -> K ds_read latency hidden under previous j's SM/PV.
//  - all 4 V fragments for j are read BEFORE the softmax chain -> V latency hides under
//    the exp2/cvt VALU (~200cy) instead of stalling PV.
//  - f32->f16 via packed cvt_pkrtz (halves cvt instruction count); result received as
//    __fp16x2 (builtin's native type) and reinterpreted through the union.
__global__ __launch_bounds__(256, 3) void attn_kernel(const short* __restrict__ Q,
                                                      const short* __restrict__ K,
                                                      const _Float16* __restrict__ Vt,
                                                      short* __restrict__ Y) {
    __shared__ __align__(16) short    Ks[2][128 * 64];   // 2 x 16384 B, swizzled
    __shared__ __align__(16) _Float16 Vs[64 * 128];      // 16384 B, swizzled

    int tid = threadIdx.x;
    int w = tid >> 6, lane = tid & 63, quad = lane >> 4, l15 = lane & 15;
    int idx = blockIdx.x;
    int qi = 15 - (idx >> 6);   // longest blocks first
    int bh = idx & 63;

    const short* Qh = Q + bh * 2048 * 64;
    const short* Kh = K + bh * 2048 * 64;
    const _Float16* Vh = Vt + bh * 64 * 2048;

    // Q fragments (B-operand: lane l15 = q, k = quad*8+j)
    bf16x8 qf[2][2];
    #pragma unroll
    for (int i = 0; i < 2; ++i)
        #pragma unroll
        for (int kh = 0; kh < 2; ++kh) {
            int t = qi * 128 + w * 32 + i * 16 + l15;
            qf[i][kh] = *(const bf16x8*)&Qh[t * 64 + kh * 32 + quad * 8];
        }

    int krow = lane >> 3;
    int kchunk = ((lane & 7) ^ krow) * 8;
    int vrow = lane >> 4;
    int vchunk = ((lane & 15) ^ (w * 4 + vrow)) * 8;

    int t7 = l15 & 7;
    int kf0_off = ((quad ^ t7) * 8);
    int kf1_off = (((quad + 4) ^ t7) * 8);
    int vsub = (quad & 1) * 4;
    int vchi = quad >> 1;

    f32x4 o[2][4] = {};
    float lsum[2] = {0.f, 0.f};

#define STGK(si_, buf_) do { \
    const short* Kt_ = Kh + (si_) * 128 * 64; \
    _Pragma("unroll") \
    for (int it = 0; it < 4; ++it) { \
        int kr0 = it * 32 + w * 8; \
        __builtin_amdgcn_global_load_lds( \
            (const __attribute__((address_space(1))) unsigned int*)&Kt_[(kr0 + krow) * 64 + kchunk], \
            (__attribute__((address_space(3))) unsigned int*)&Ks[buf_][kr0 * 64], 16, 0, 0); \
    } } while (0)
#define STGV(si_) do { \
    const _Float16* Vp_ = Vh + (si_) * 128; \
    _Pragma("unroll") \
    for (int it = 0; it < 4; ++it) { \
        int vr0 = it * 16 + w * 4; \
        __builtin_amdgcn_global_load_lds( \
            (const __attribute__((address_space(1))) unsigned int*)&Vp_[(vr0 + vrow) * 2048 + vchunk], \
            (__attribute__((address_space(3))) unsigned int*)&Vs[vr0 * 128], 16, 0, 0); \
    } } while (0)

    STGK(0, 0);
    STGV(0);

    for (int si = 0; si <= qi; ++si) {
        // top: only K(si)+V(si) are outstanding -> plain drain, then publish
        asm volatile("s_waitcnt vmcnt(0)" ::: "memory");
        __builtin_amdgcn_s_barrier();
        __builtin_amdgcn_sched_barrier(0);

        if (si < qi) STGK(si + 1, (si + 1) & 1);   // hidden under this iter's j-loop

        const short* Ksb = Ks[si & 1];
        bool diag = (si == qi);

        // pipelined j-loop: kf pre-read one iteration ahead
        bf16x8 kfP0 = *(const bf16x8*)&Ksb[l15 * 64 + kf0_off];
        bf16x8 kfP1 = *(const bf16x8*)&Ksb[l15 * 64 + kf1_off];

        #pragma unroll
        for (int j = 0; j < 8; ++j) {
            // QK(j): issue first — operands were read last iteration
            f32x4 av[2];
            #pragma unroll
            for (int i = 0; i < 2; ++i) {
                f32x4 t = {};
                t = __builtin_amdgcn_mfma_f32_16x16x32_bf16(kfP0, qf[i][0], t, 0, 0, 0);
                t = __builtin_amdgcn_mfma_f32_16x16x32_bf16(kfP1, qf[i][1], t, 0, 0, 0);
                av[i] = t;
            }
            // prefetch kf(j+1) — latency hidden under this j's SM+PV
            bf16x8 kfN0, kfN1;
            if (j < 7) {
                int trowN = ((j + 1) * 16 + l15) * 64;
                kfN0 = *(const bf16x8*)&Ksb[trowN + kf0_off];
                kfN1 = *(const bf16x8*)&Ksb[trowN + kf1_off];
            }
            // V reads hoisted BEFORE the softmax chain — latency hidden under exp2/cvt
            int vc = (j * 2 + vchi);
            f16x4 vf[4];
            #pragma unroll
            for (int mt = 0; mt < 4; ++mt)
                vf[mt] = *(const f16x4*)&Vs[(mt * 16 + l15) * 128 + ((vc ^ l15) * 8) + vsub];
            // softmax on av
            f16x4 pfv[2];
            #pragma unroll
            for (int i = 0; i < 2; ++i) {
                f32x4 a = av[i];
                if (diag) {
                    int qrel = w * 32 + i * 16 + l15;
                    #pragma unroll
                    for (int r = 0; r < 4; ++r)
                        if (j * 16 + quad * 4 + r > qrel) a[r] = -1e30f;
                }
                float p0 = __builtin_amdgcn_exp2f(a[0]);
                float p1 = __builtin_amdgcn_exp2f(a[1]);
                float p2 = __builtin_amdgcn_exp2f(a[2]);
                float p3 = __builtin_amdgcn_exp2f(a[3]);
                lsum[i] += (p0 + p1) + (p2 + p3);
                union { fp16x2 h2[2]; f16x4 h4; } pu;
                pu.h2[0] = __builtin_amdgcn_cvt_pkrtz(p0, p1);
                pu.h2[1] = __builtin_amdgcn_cvt_pkrtz(p2, p3);
                pfv[i] = pu.h4;
            }
            // PV(j)
            #pragma unroll
            for (int mt = 0; mt < 4; ++mt) {
                o[0][mt] = __builtin_amdgcn_mfma_f32_16x16x16f16(vf[mt], pfv[0], o[0][mt], 0, 0, 0);
                o[1][mt] = __builtin_amdgcn_mfma_f32_16x16x16f16(vf[mt], pfv[1], o[1][mt], 0, 0, 0);
            }
            if (j < 7) { kfP0 = kfN0; kfP1 = kfN1; }
        }

        if (si < qi) {
            asm volatile("s_waitcnt lgkmcnt(0)" ::: "memory");  // all Vs (and Ks) reads complete
            __builtin_amdgcn_s_barrier();                        // every wave past its reads
            __builtin_amdgcn_sched_barrier(0);
            STGV(si + 1);                                        // deadline: next iter's PV
        }
    }
#undef STGK
#undef STGV

    int b = bh >> 4, h = bh & 15;
    #pragma unroll
    for (int i = 0; i < 2; ++i) {
        float l = lsum[i];
        l += __shfl_xor(l, 16);
        l += __shfl_xor(l, 32);
        float rinv = 1.0f / l;
        int q = qi * 128 + w * 32 + i * 16 + l15;
        short* yrow = &Y[(b * 2048 + q) * 1024 + h * 64];
        #pragma unroll
        for (int mt = 0; mt < 4; ++mt) {
            short4 s4;
            s4.x = f2b(o[i][mt][0] * rinv);
            s4.y = f2b(o[i][mt][1] * rinv);
            s4.z = f2b(o[i][mt][2] * rinv);
            s4.w = f2b(o[i][mt][3] * rinv);
            *(short4*)&yrow[mt * 16 + quad * 4] = s4;
        }
    }
}

// ----------------------------------------------------------------
extern "C" void kernel_launch(void* const* d_in, const int* in_sizes, int n_in,
                              void* d_out, int out_size, void* d_ws, size_t ws_size,
                              hipStream_t stream) {
    const float* x  = (const float*)d_in[0];
    const float* Wk = (const float*)d_in[1];
    const float* bk = (const float*)d_in[2];
    const float* Wq = (const float*)d_in[3];
    const float* bq = (const float*)d_in[4];
    const float* Wv = (const float*)d_in[5];
    const float* bv = (const float*)d_in[6];
    const float* Wp = (const float*)d_in[7];
    const float* bp = (const float*)d_in[8];

    char* ws = (char*)d_ws;
    short*     xb  = (short*)(ws + 0);          // 16 MB  x bf16 [8192][1024]
    short*     Wqt = (short*)(ws + 16777216);   // 2 MB each, bf16 [N][K]
    short*     Wkt = (short*)(ws + 18874368);
    short*     Wvt = (short*)(ws + 20971520);
    short*     Wpt = (short*)(ws + 23068672);
    short*     Qb  = (short*)(ws + 25165824);   // 16 MB [B,H,T,D] (pre-scaled by log2e/8)
    short*     Kb  = (short*)(ws + 41943040);   // 16 MB [B,H,T,D]
    _Float16*  Vtb = (_Float16*)(ws + 75497472);// 16 MB [B,H,D,T] f16 (written directly by gemm z=2)
    short*     Yb  = (short*)(ws + 92274688);   // 16 MB [B*T][C]

    prep_kernel<<<9216, 256, 0, stream>>>(x, xb, Wq, Wk, Wv, Wp, Wqt, Wkt, Wvt, Wpt);
    gemm8_kernel<0><<<dim3(64, 4, 3), 512, 0, stream>>>(xb, Wqt, Wkt, Wvt, bq, bk, bv,
                                                        0.18033688011112042f /* log2e/8 */, 1.0f, 1.0f,
                                                        (void*)Qb, (void*)Kb, (void*)Vtb);
    attn_kernel<<<1024, 256, 0, stream>>>(Qb, Kb, Vtb, Yb);
    gemm8_kernel<1><<<dim3(64, 4, 1), 512, 0, stream>>>(Yb, Wpt, nullptr, nullptr,
                                                        bp, nullptr, nullptr,
                                                        1.0f, 1.0f, 1.0f,
                                                        (void*)d_out, nullptr, nullptr);
}